// Round 4
// baseline (482.262 us; speedup 1.0000x reference)
//
#include <hip/hip_runtime.h>

typedef _Float16 half8_t __attribute__((ext_vector_type(8)));
typedef _Float16 half4_t __attribute__((ext_vector_type(4)));
typedef float floatx4 __attribute__((ext_vector_type(4)));

// async global->LDS, 16B per lane. lds ptr wave-uniform; HW writes lane L at
// ldsbase + L*16.
__device__ inline void gload16(const void* g, void* l) {
  __builtin_amdgcn_global_load_lds(
      (const __attribute__((address_space(1))) unsigned int*)g,
      (__attribute__((address_space(3))) unsigned int*)l, 16, 0, 0);
}

// ================== 256x256 pipelined-unit BT GEMM =======================
// C[m,n] = sum_h A[m,h]*B[n,h] (+bias). fp16, K-contiguous rows, K=1024.
// 512 threads = 8 waves (2 row x 4 col per 128x128 quadrant).
// LDS layout per operand per parity: 256 rows x 64 k fp16, chunk-transposed:
// 16B chunk (kb,m) at offset (kb*256+m)*16. Conflict-free for gload_lds
// (linear dest) and ds_read_b128 (lanes 0-15 -> consecutive chunks).
//
// K-tile = 8 units of 8 MFMA, Gray path over (qm,qn,kk):
//   u0(0,0,k0) u1(0,1,k0) u2(1,1,k0) u3(1,0,k0)
//   u4(1,0,k1) u5(1,1,k1) u6(0,1,k1) u7(0,0,k1)
// Each step changes ONE frag set -> ds_reads for unit i+1 issue during unit
// i's MFMAs (register double-buffer af_a/af_b, bfA/bfB). 24 reads/K-tile.
// Stages (tile t+2, same parity p, into slots proven dead):
//   u4: A1+B0   u5: B1   u6: A0
// HARDENED vs r3: every pre-stage wait is lgkmcnt(0) (emission-order-robust;
// each drained read was issued before the PREVIOUS unit's MFMA cluster, so
// the wait is already satisfied -> no stall), and each unit's prefetch
// ds_read is issued AFTER its barrier (never targets a slot being staged).
// u7: vmcnt(8) drains tile t+1's 8 stage-loads (t+2's 8 stay in flight),
// barrier, then prefetch next tile's A00/B00 frags from parity q.
// Barriers: 4/K-tile. vmcnt never 0 in the loop.
constexpr int NT = 16;  // K / 64

// load one A frag-set: 4 x ds_read_b128 at (kk,qm)
__device__ inline void lda1(const char* sA, int kk, int qm, int wr, int quad,
                            int mrow, half8_t af[4]) {
#pragma unroll
  for (int mf = 0; mf < 4; ++mf)
    af[mf] = *(const half8_t*)(
        sA + (size_t)(((kk * 4 + quad) * 256 + qm * 128 + wr * 64 + mf * 16 +
                       mrow) << 4));
}

// load one B frag-set: 2 x ds_read_b128 at (kk,qn)
__device__ inline void ldb1(const char* sB, int kk, int qn, int wc, int quad,
                            int mrow, half8_t bf[2]) {
#pragma unroll
  for (int nf = 0; nf < 2; ++nf)
    bf[nf] = *(const half8_t*)(
        sB + (size_t)(((kk * 4 + quad) * 256 + qn * 128 + wc * 32 + nf * 16 +
                       mrow) << 4));
}

template <int QM, int QN>
__device__ inline void mfma8(const half8_t af[4], const half8_t bf[2],
                             floatx4 acc[8][4]) {
  __builtin_amdgcn_s_setprio(1);
#pragma unroll
  for (int mf = 0; mf < 4; ++mf)
#pragma unroll
    for (int nf = 0; nf < 2; ++nf)
      acc[QM * 4 + mf][QN * 2 + nf] = __builtin_amdgcn_mfma_f32_16x16x32_f16(
          af[mf], bf[nf], acc[QM * 4 + mf][QN * 2 + nf], 0, 0, 0);
  __builtin_amdgcn_s_setprio(0);
}

// stage half h (rows [h*128,h*128+128)) of K-tile u of operand X (X already
// includes the block tile offset). 2 gload16/wave; wave wid covers kb=wid.
__device__ inline void stage_half(const _Float16* __restrict__ X, int ldx,
                                  int u, char* opbase, int h, int wid,
                                  int lane) {
#pragma unroll
  for (int i = 0; i < 2; ++i) {
    gload16(X + (long)(h * 128 + i * 64 + lane) * ldx + u * 64 + wid * 8,
            opbase + (size_t)((wid * 256 + h * 128 + i * 64) << 4));
  }
}

template <typename OT, int BIAS, int GX, int GY>
__global__ __launch_bounds__(512, 2) void gemm256(
    const _Float16* __restrict__ A, long As, int lda,
    const _Float16* __restrict__ B, long Bs, int ldb,
    OT* __restrict__ C, long Cs, int ldc,
    const float* __restrict__ bias, int biasStride) {
  __shared__ char smem[131072];  // A: p*32768, B: 65536 + p*32768

  // XCD chunk swizzle (grids are 256/512, always %8==0)
  const int id = blockIdx.x;
  const int chunk = gridDim.x >> 3;
  const int nid = (id & 7) * chunk + (id >> 3);
  const int bx = nid % GX;
  const int by = (nid / GX) % GY;
  const int bz = nid / (GX * GY);

  const int tid = threadIdx.x;
  const int lane = tid & 63;
  const int wid = tid >> 6;
  const int wr = wid >> 2;   // 0..1
  const int wc = wid & 3;    // 0..3
  const int quad = lane >> 4;
  const int mrow = lane & 15;
  const long m0 = (long)by * 256;
  const long n0 = (long)bx * 256;
  const _Float16* Ab = A + (long)bz * As + m0 * (long)lda;
  const _Float16* Bb = B + (long)bz * Bs + n0 * (long)ldb;
  C += (long)bz * Cs;

  floatx4 acc[8][4] = {};
  half8_t af_a[4], af_b[4], bfA[2], bfB[2];

  // ---- prologue: stage t0 (parity0) + t1 (parity1); drain t0; preload u0.
  {
    char* sA0 = smem;
    char* sB0 = smem + 65536;
    char* sA1 = smem + 32768;
    char* sB1 = smem + 65536 + 32768;
    stage_half(Ab, lda, 0, sA0, 0, wid, lane);
    stage_half(Ab, lda, 0, sA0, 1, wid, lane);
    stage_half(Bb, ldb, 0, sB0, 0, wid, lane);
    stage_half(Bb, ldb, 0, sB0, 1, wid, lane);
    stage_half(Ab, lda, 1, sA1, 0, wid, lane);
    stage_half(Ab, lda, 1, sA1, 1, wid, lane);
    stage_half(Bb, ldb, 1, sB1, 0, wid, lane);
    stage_half(Bb, ldb, 1, sB1, 1, wid, lane);
    asm volatile("s_waitcnt vmcnt(8)" ::: "memory");
    __builtin_amdgcn_s_barrier();
    lda1(sA0, 0, 0, wr, quad, mrow, af_a);  // A00(t0)
    ldb1(sB0, 0, 0, wc, quad, mrow, bfA);   // B00(t0)
  }

  for (int t = 0; t < NT; ++t) {
    const int p = t & 1, q = p ^ 1;
    char* sAc = smem + p * 32768;
    char* sBc = smem + 65536 + p * 32768;
    char* sAn = smem + q * 32768;
    char* sBn = smem + 65536 + q * 32768;
    // clamped tail re-stages keep issue counts uniform; duplicates land in
    // dead-or-identical slots only.
    const int tu = (t + 2 < NT) ? t + 2 : NT - 1;

    // u0 (0,0,k0): af_a,bfA; prefetch B10->bfB
    ldb1(sBc, 0, 1, wc, quad, mrow, bfB);
    mfma8<0, 0>(af_a, bfA, acc);
    // u1 (0,1,k0): af_a,bfB; prefetch A10->af_b
    lda1(sAc, 0, 1, wr, quad, mrow, af_b);
    mfma8<0, 1>(af_a, bfB, acc);
    // u2 (1,1,k0): af_b,bfB
    mfma8<1, 1>(af_b, bfB, acc);
    // u3 (1,0,k0): af_b,bfA; prefetch A11->af_a, B01->bfB
    lda1(sAc, 1, 1, wr, quad, mrow, af_a);
    ldb1(sBc, 1, 0, wc, quad, mrow, bfB);
    mfma8<1, 0>(af_b, bfA, acc);
    // u4 (1,0,k1): af_a,bfB. Drain ALL ds_reads (A11,B01 issued before u3's
    // MFMA cluster -> no stall); A1,B0 slots dead for all waves after the
    // barrier; stage them; then prefetch B11 (B1 slot, disjoint).
    asm volatile("s_waitcnt lgkmcnt(0)" ::: "memory");
    __builtin_amdgcn_s_barrier();
    stage_half(Ab, lda, tu, sAc, 1, wid, lane);
    stage_half(Bb, ldb, tu, sBc, 0, wid, lane);
    ldb1(sBc, 1, 1, wc, quad, mrow, bfA);  // B11 prefetch
    mfma8<1, 0>(af_a, bfB, acc);
    // u5 (1,1,k1): af_a,bfA. Drain (B11 issued before u4's MFMAs -> no
    // stall); B1 slot dead; stage it; prefetch A01 (A0 slot).
    asm volatile("s_waitcnt lgkmcnt(0)" ::: "memory");
    __builtin_amdgcn_s_barrier();
    stage_half(Bb, ldb, tu, sBc, 1, wid, lane);
    lda1(sAc, 1, 0, wr, quad, mrow, af_b);  // A01 prefetch
    mfma8<1, 1>(af_a, bfA, acc);
    // u6 (0,1,k1): af_b,bfA. Drain (A01 issued before u5's MFMAs); A0 slot
    // dead; stage it.
    asm volatile("s_waitcnt lgkmcnt(0)" ::: "memory");
    __builtin_amdgcn_s_barrier();
    stage_half(Ab, lda, tu, sAc, 0, wid, lane);
    mfma8<0, 1>(af_b, bfA, acc);
    // u7 (0,0,k1): af_b,bfB. Parity switch: drain tile t+1's 8 stage-loads
    // (t+2's 8 stay in flight); prefetch next tile's A00/B00 from parity q.
    asm volatile("s_waitcnt vmcnt(8)" ::: "memory");
    __builtin_amdgcn_s_barrier();
    lda1(sAn, 0, 0, wr, quad, mrow, af_a);  // A00(t+1)
    ldb1(sBn, 0, 0, wc, quad, mrow, bfA);   // B00(t+1)
    mfma8<0, 0>(af_b, bfB, acc);
  }

  asm volatile("s_waitcnt vmcnt(0)" ::: "memory");

  // epilogue: C/D layout col = lane&15, row = quad*4 + r (per 16x16 frag)
#pragma unroll
  for (int mh = 0; mh < 2; ++mh)
#pragma unroll
    for (int mf = 0; mf < 4; ++mf) {
      const int rbase = mh * 128 + wr * 64 + mf * 16 + quad * 4;
#pragma unroll
      for (int nh = 0; nh < 2; ++nh)
#pragma unroll
        for (int nf = 0; nf < 2; ++nf) {
          const int cc = (int)n0 + nh * 128 + wc * 32 + nf * 16 + mrow;
#pragma unroll
          for (int r = 0; r < 4; ++r) {
            const long row = m0 + rbase + r;
            float v = acc[mh * 4 + mf][nh * 2 + nf][r];
            if constexpr (BIAS == 1) v += bias[bz * biasStride + cc];
            if constexpr (BIAS == 2) v += bias[(int)row];
            C[row * (long)ldc + cc] = (OT)v;
          }
        }
    }
}

// ===================== auxiliary kernels (unchanged) =====================

__global__ __launch_bounds__(256) void convert_x(const float* __restrict__ x0,
                                                 const float* __restrict__ x1,
                                                 const float* __restrict__ x2,
                                                 _Float16* __restrict__ out) {
  int i = blockIdx.x * 256 + threadIdx.x;  // 12582912 chunks total
  int t = i >> 22;                         // 4194304 chunks per tensor
  int j = i & 4194303;
  const float* src = (t == 0) ? x0 : (t == 1) ? x1 : x2;
  floatx4 v = ((const floatx4*)src)[j];
  half4_t h = {(_Float16)v[0], (_Float16)v[1], (_Float16)v[2], (_Float16)v[3]};
  ((half4_t*)out)[i] = h;
}

__global__ __launch_bounds__(256) void convert_w(const float* __restrict__ Wq,
                                                 const float* __restrict__ Wk,
                                                 const float* __restrict__ Wv,
                                                 _Float16* __restrict__ out) {
  int i = blockIdx.x * 256 + threadIdx.x;  // 786432 chunks total
  int t = i >> 18;                         // 262144 chunks per tensor
  int j = i & 262143;
  const float* src = (t == 0) ? Wq : (t == 1) ? Wk : Wv;
  floatx4 v = ((const floatx4*)src)[j];
  half4_t h = {(_Float16)v[0], (_Float16)v[1], (_Float16)v[2], (_Float16)v[3]};
  ((half4_t*)out)[i] = h;
}

__global__ __launch_bounds__(256) void pack_bias(const float* __restrict__ bq,
                                                 const float* __restrict__ bk,
                                                 const float* __restrict__ bv,
                                                 float* __restrict__ out) {
  int b = blockIdx.x;
  const float* src = (b == 0) ? bq : (b == 1) ? bk : bv;
  ((floatx4*)out)[b * 256 + threadIdx.x] =
      ((const floatx4*)src)[threadIdx.x];
}

// Row softmax over 1024 fp16 scores, fp32 math, fp16 result in place.
__global__ __launch_bounds__(256) void softmax_rows_h(_Float16* __restrict__ S) {
  long row = blockIdx.x;
  _Float16* Sr = S + row * 1024;
  int tid = threadIdx.x, lane = tid & 63, wid = tid >> 6;
  half4_t x = ((const half4_t*)Sr)[tid];
  float x0 = x[0], x1 = x[1], x2 = x[2], x3 = x[3];
  float mx = fmaxf(fmaxf(x0, x1), fmaxf(x2, x3));
#pragma unroll
  for (int off = 32; off > 0; off >>= 1) mx = fmaxf(mx, __shfl_xor(mx, off));
  __shared__ float redm[4];
  if (lane == 0) redm[wid] = mx;
  __syncthreads();
  mx = fmaxf(fmaxf(redm[0], redm[1]), fmaxf(redm[2], redm[3]));
  float e0 = __expf(x0 - mx), e1 = __expf(x1 - mx);
  float e2 = __expf(x2 - mx), e3 = __expf(x3 - mx);
  float s = e0 + e1 + e2 + e3;
#pragma unroll
  for (int off = 32; off > 0; off >>= 1) s += __shfl_xor(s, off);
  __shared__ float reds[4];
  if (lane == 0) reds[wid] = s;
  __syncthreads();
  s = reds[0] + reds[1] + reds[2] + reds[3];
  float inv = 1.0f / s;
  half4_t h = {(_Float16)(e0 * inv), (_Float16)(e1 * inv),
               (_Float16)(e2 * inv), (_Float16)(e3 * inv)};
  ((half4_t*)Sr)[tid] = h;
}

extern "C" void kernel_launch(void* const* d_in, const int* in_sizes, int n_in,
                              void* d_out, int out_size, void* d_ws,
                              size_t ws_size, hipStream_t stream) {
  (void)in_sizes; (void)n_in; (void)out_size; (void)ws_size;
  const float* meme  = (const float*)d_in[0];
  const float* text  = (const float*)d_in[1];
  const float* emoji = (const float*)d_in[2];
  const float* Wq = (const float*)d_in[3];
  const float* bq = (const float*)d_in[4];
  const float* Wk = (const float*)d_in[5];
  const float* bk = (const float*)d_in[6];
  const float* Wv = (const float*)d_in[7];
  const float* bv = (const float*)d_in[8];

  const long MB = 1024 * 1024;
  char* ws = (char*)d_ws;
  _Float16* hWq = (_Float16*)ws;
  float* pbias  = (float*)(ws + 6 * MB);
  _Float16* mh  = (_Float16*)(ws + 7 * MB);
  _Float16* th  = (_Float16*)(ws + 39 * MB);
  _Float16* eh  = (_Float16*)(ws + 71 * MB);
  _Float16* Qh  = (_Float16*)(ws + 103 * MB);
  _Float16* Kh  = (_Float16*)(ws + 135 * MB);
  _Float16* S   = mh;  // aliases meme_h (dead by then)
  _Float16* Vt  = th;  // aliases text_h (dead by then)
  _Float16* hWv = hWq + 2 * MB;

  dim3 blk(256), blk5(512);
  convert_w<<<3072, blk, 0, stream>>>(Wq, Wk, Wv, hWq);
  pack_bias<<<3, blk, 0, stream>>>(bq, bk, bv, pbias);
  convert_x<<<49152, blk, 0, stream>>>(meme, text, emoji, mh);

  // Q,K projections batched (z=2): M=16384 (GY=64), N=1024 (GX=4).
  gemm256<_Float16, 1, 4, 64><<<dim3(512), blk5, 0, stream>>>(
      mh, 16777216, 1024, hWq, 1048576, 1024, Qh, 16777216, 1024, pbias, 1024);
  // Vt[a, b*L+l] = sum_h Wv[a,h]*emoji[b,l,h] + bv[a]  (V transposed)
  gemm256<_Float16, 2, 64, 4><<<dim3(256), blk5, 0, stream>>>(
      hWv, 0, 1024, eh, 0, 1024, Vt, 0, 16384, pbias + 2048, 0);
  // S[b] = Q[b] @ K[b]^T -> fp16. per-batch 1024x1024, z=16.
  gemm256<_Float16, 0, 4, 4><<<dim3(256), blk5, 0, stream>>>(
      Qh, 1048576, 1024, Kh, 1048576, 1024, S, 1048576, 1024, nullptr, 0);
  // softmax rows, fp16 in place
  softmax_rows_h<<<16384, blk, 0, stream>>>(S);
  // O[b] = P[b] @ V[b] via Vt: C[q,a] = sum_k P[q,k] * Vt[a, b*1024+k]
  gemm256<float, 0, 4, 4><<<dim3(256), blk5, 0, stream>>>(
      S, 1048576, 1024, Vt, 1024, 16384, (float*)d_out, 1048576, 1024,
      nullptr, 0);
}